// Round 2
// baseline (2983.982 us; speedup 1.0000x reference)
//
#include <hip/hip_runtime.h>
#include <math.h>

#define B_    16
#define NP_   64
#define J_    17
#define C_    480
#define H_    128
#define W_    128
#define L_    4
#define HW_   (H_ * W_)
#define NSAMP (B_ * NP_)      // 1024
#define MROWS (NSAMP * J_)    // 17408
#define EPS_  1e-5f

// ---------------- bilinear joint sampling ----------------
// one block per point p = (b*NP+np)*J + j ; threads over channels
__global__ __launch_bounds__(256) void k_sample(const float* __restrict__ feat,
                                                const float* __restrict__ coords,
                                                float* __restrict__ X) {
    int p  = blockIdx.x;          // 0..MROWS-1
    int bn = p / J_;              // b*NP+np
    int b  = bn / NP_;
    float x = coords[p * 2 + 0];
    float y = coords[p * 2 + 1];
    float x0f = fminf(fmaxf(floorf(x), 0.f), (float)(W_ - 2));
    float y0f = fminf(fmaxf(floorf(y), 0.f), (float)(H_ - 2));
    int x0 = (int)x0f, y0 = (int)y0f;
    float wx = x - x0f, wy = y - y0f;
    float w00 = (1.f - wx) * (1.f - wy);
    float w01 = wx * (1.f - wy);
    float w10 = (1.f - wx) * wy;
    float w11 = wx * wy;
    int i00 = y0 * W_ + x0;
    const float* base = feat + (size_t)b * C_ * HW_;
    for (int c = threadIdx.x; c < C_; c += 256) {
        const float* pc = base + (size_t)c * HW_ + i00;
        float v = pc[0] * w00 + pc[1] * w01 + pc[W_] * w10 + pc[W_ + 1] * w11;
        X[(size_t)p * C_ + c] = v;
    }
}

// ---------------- center gather ----------------
__global__ __launch_bounds__(256) void k_center(const float* __restrict__ feat,
                                                const int* __restrict__ cidx,
                                                float* __restrict__ Cf) {
    int bn = blockIdx.x;          // 0..NSAMP-1
    int b  = bn / NP_;
    int idx = cidx[bn];
    const float* base = feat + (size_t)b * C_ * HW_ + idx;
    for (int c = threadIdx.x; c < C_; c += 256)
        Cf[(size_t)bn * C_ + c] = base[(size_t)c * HW_];
}

// ---------------- adjacency mix: Xout[n,j,:] = sum_k adj[j,k] Xin[n,k,:] ----------------
__global__ __launch_bounds__(256) void k_mix(const float* __restrict__ Xin,
                                             const float* __restrict__ adj,
                                             float* __restrict__ Xout) {
    __shared__ float sadj[J_ * J_];
    for (int t = threadIdx.x; t < J_ * J_; t += 256) sadj[t] = adj[t];  // J*J=289 > 256: must stride
    __syncthreads();
    int n = blockIdx.x;
    const float* xb = Xin + (size_t)n * J_ * C_;
    float* yb = Xout + (size_t)n * J_ * C_;
    for (int c = threadIdx.x; c < C_; c += 256) {
        float xv[J_];
        #pragma unroll
        for (int k = 0; k < J_; k++) xv[k] = xb[(size_t)k * C_ + c];
        #pragma unroll
        for (int j = 0; j < J_; j++) {
            float s = 0.f;
            #pragma unroll
            for (int k = 0; k < J_; k++) s += sadj[j * J_ + k] * xv[k];
            yb[(size_t)j * C_ + c] = s;
        }
    }
}

// ---------------- tiled f32 GEMM with fused bias + BN + ReLU (+ residual add) ----------------
// out[m,c] = relu(bn(sum_k A[m,k]*B(k,c) + bias[c])) (+ res[m,c])
// BT=false: B row-major [K,N].  BT=true: B row-major [N,K] (use B[c,k]).
// BM=BN=128, BK=16, 256 threads, 8x8 per thread. M must be divisible by 128; K by 16.
template <bool BT, bool ADD>
__global__ __launch_bounds__(256) void k_gemm(const float* __restrict__ A,
                                              const float* __restrict__ Bm,
                                              const float* __restrict__ bias,
                                              const float* __restrict__ bn,
                                              const float* res,      // no restrict: may alias out
                                              float* out,
                                              int M, int N, int K) {
    __shared__ float As[16][132];  // [k][row], padded
    __shared__ float Bs[16][132];  // [k][col], padded
    const int tid = threadIdx.x;
    const int tx = tid & 15, ty = tid >> 4;
    const int row0 = blockIdx.y * 128;
    const int col0 = blockIdx.x * 128;

    float acc[8][8];
    #pragma unroll
    for (int i = 0; i < 8; i++)
        #pragma unroll
        for (int j = 0; j < 8; j++) acc[i][j] = 0.f;

    for (int kk = 0; kk < K; kk += 16) {
        // --- load A tile (transposed into LDS) ---
        {
            int r  = tid >> 2;        // 0..63
            int v4 = (tid & 3) * 4;   // col within the 16-wide k slab
            #pragma unroll
            for (int h = 0; h < 2; h++) {
                int rr = r + h * 64;
                float4 a = *reinterpret_cast<const float4*>(
                    &A[(size_t)(row0 + rr) * K + kk + v4]);
                As[v4 + 0][rr] = a.x;
                As[v4 + 1][rr] = a.y;
                As[v4 + 2][rr] = a.z;
                As[v4 + 3][rr] = a.w;
            }
        }
        // --- load B tile ---
        if (!BT) {
            int k0 = tid >> 5;            // 0..7
            int c4 = (tid & 31) * 4;      // 0..124
            #pragma unroll
            for (int h = 0; h < 2; h++) {
                int k = k0 + h * 8;
                float4 v = make_float4(0.f, 0.f, 0.f, 0.f);
                int col = col0 + c4;
                if (col < N)
                    v = *reinterpret_cast<const float4*>(&Bm[(size_t)(kk + k) * N + col]);
                *reinterpret_cast<float4*>(&Bs[k][c4]) = v;
            }
        } else {
            int cr = tid >> 2;            // 0..63
            int k4 = (tid & 3) * 4;
            #pragma unroll
            for (int h = 0; h < 2; h++) {
                int cc = cr + h * 64;
                int col = col0 + cc;
                float4 v = make_float4(0.f, 0.f, 0.f, 0.f);
                if (col < N)
                    v = *reinterpret_cast<const float4*>(&Bm[(size_t)col * K + kk + k4]);
                Bs[k4 + 0][cc] = v.x;
                Bs[k4 + 1][cc] = v.y;
                Bs[k4 + 2][cc] = v.z;
                Bs[k4 + 3][cc] = v.w;
            }
        }
        __syncthreads();
        // --- compute ---
        #pragma unroll
        for (int k = 0; k < 16; k++) {
            float4 a0 = *reinterpret_cast<const float4*>(&As[k][ty * 8]);
            float4 a1 = *reinterpret_cast<const float4*>(&As[k][ty * 8 + 4]);
            float4 b0 = *reinterpret_cast<const float4*>(&Bs[k][tx * 8]);
            float4 b1 = *reinterpret_cast<const float4*>(&Bs[k][tx * 8 + 4]);
            float av[8] = {a0.x, a0.y, a0.z, a0.w, a1.x, a1.y, a1.z, a1.w};
            float bv[8] = {b0.x, b0.y, b0.z, b0.w, b1.x, b1.y, b1.z, b1.w};
            #pragma unroll
            for (int i = 0; i < 8; i++)
                #pragma unroll
                for (int j = 0; j < 8; j++)
                    acc[i][j] = fmaf(av[i], bv[j], acc[i][j]);
        }
        __syncthreads();
    }

    // --- epilogue: bias + BN + ReLU (+ add) ---
    #pragma unroll
    for (int i = 0; i < 8; i++) {
        int row = row0 + ty * 8 + i;
        #pragma unroll
        for (int j = 0; j < 8; j++) {
            int col = col0 + tx * 8 + j;
            if (col < N) {
                float v  = acc[i][j] + bias[col];
                float g  = bn[col];
                float be = bn[N + col];
                float mu = bn[2 * N + col];
                float va = bn[3 * N + col];
                v = (v - mu) * rsqrtf(va + EPS_) * g + be;
                v = fmaxf(v, 0.f);
                if (ADD) v += res[(size_t)row * N + col];
                out[(size_t)row * N + col] = v;
            }
        }
    }
}

// ---------------- pooling + concat: feats = [mean_j h, max_j h, center] ----------------
__global__ __launch_bounds__(256) void k_pool(const float* __restrict__ Hb,
                                              const float* __restrict__ Cen,
                                              float* __restrict__ feats) {
    int n = blockIdx.x;
    for (int c = threadIdx.x; c < C_; c += 256) {
        float s = 0.f, m = -INFINITY;
        #pragma unroll
        for (int j = 0; j < J_; j++) {
            float v = Hb[((size_t)n * J_ + j) * C_ + c];
            s += v;
            m = fmaxf(m, v);
        }
        feats[(size_t)n * 3 * C_ + c]          = s * (1.f / (float)J_);
        feats[(size_t)n * 3 * C_ + C_ + c]     = m;
        feats[(size_t)n * 3 * C_ + 2 * C_ + c] = Cen[(size_t)n * C_ + c];
    }
}

// ---------------- final projection: out[m,o] = sum_k P[m,k]*Wp2[o,k] + bp2[o] ----------------
__global__ __launch_bounds__(256) void k_final(const float* __restrict__ P,
                                               const float* __restrict__ W2,
                                               const float* __restrict__ b2,
                                               float* __restrict__ out) {
    int g = blockIdx.x * 256 + threadIdx.x;
    if (g >= NSAMP * 2 * J_) return;
    int m = g / (2 * J_);
    int o = g % (2 * J_);
    const float* pr = P + (size_t)m * C_;
    const float* wr = W2 + (size_t)o * C_;
    float s = 0.f;
    for (int k = 0; k < C_; k += 4) {
        s = fmaf(pr[k + 0], wr[k + 0], s);
        s = fmaf(pr[k + 1], wr[k + 1], s);
        s = fmaf(pr[k + 2], wr[k + 2], s);
        s = fmaf(pr[k + 3], wr[k + 3], s);
    }
    out[g] = s + b2[o];
}

extern "C" void kernel_launch(void* const* d_in, const int* in_sizes, int n_in,
                              void* d_out, int out_size, void* d_ws, size_t ws_size,
                              hipStream_t stream) {
    const float* features = (const float*)d_in[0];
    const float* coords   = (const float*)d_in[1];
    const int*   center   = (const int*)d_in[2];
    const float* adj      = (const float*)d_in[3];
    const float* Wh       = (const float*)d_in[4];
    const float* bh       = (const float*)d_in[5];
    const float* bn_head  = (const float*)d_in[6];
    const float* Wres     = (const float*)d_in[7];
    const float* bres     = (const float*)d_in[8];
    const float* bn_res   = (const float*)d_in[9];
    const float* Wp1      = (const float*)d_in[10];
    const float* bp1      = (const float*)d_in[11];
    const float* bn_pred  = (const float*)d_in[12];
    const float* Wp2      = (const float*)d_in[13];
    const float* bp2      = (const float*)d_in[14];
    float* out = (float*)d_out;

    float* ws   = (float*)d_ws;
    float* bufX = ws;                               // [MROWS, C]
    float* bufT = bufX + (size_t)MROWS * C_;        // [MROWS, C] mix temp / GEMM A
    float* bufH = bufT + (size_t)MROWS * C_;        // [MROWS, C] running h
    float* bufC = bufH + (size_t)MROWS * C_;        // [NSAMP, C]
    float* bufF = bufC + (size_t)NSAMP * C_;        // [NSAMP, 3C]
    float* bufP = bufF + (size_t)NSAMP * 3 * C_;    // [NSAMP, C]

    dim3 gg(4, MROWS / 128);   // N=480 -> 4 col tiles of 128 (last masked)
    dim3 gp(4, NSAMP / 128);

    k_sample<<<MROWS, 256, 0, stream>>>(features, coords, bufX);
    k_center<<<NSAMP, 256, 0, stream>>>(features, center, bufC);

    // head block: h = relu(bn(adj@(x@Wh)+bh))  ==  relu(bn((adj@x)@Wh + bh))
    k_mix<<<NSAMP, 256, 0, stream>>>(bufX, adj, bufT);
    k_gemm<false, false><<<gg, 256, 0, stream>>>(bufT, Wh, bh, bn_head, nullptr, bufH,
                                                 MROWS, C_, C_);

    for (int i = 0; i < L_; i++) {
        // gblock 1: bufH -> bufX
        k_mix<<<NSAMP, 256, 0, stream>>>(bufH, adj, bufT);
        k_gemm<false, false><<<gg, 256, 0, stream>>>(
            bufT, Wres + (size_t)(i * 2 + 0) * C_ * C_, bres + (size_t)(i * 2 + 0) * C_,
            bn_res + (size_t)(i * 2 + 0) * 4 * C_, nullptr, bufX, MROWS, C_, C_);
        // gblock 2 + residual: bufH = bufH + gblock(bufX)
        k_mix<<<NSAMP, 256, 0, stream>>>(bufX, adj, bufT);
        k_gemm<false, true><<<gg, 256, 0, stream>>>(
            bufT, Wres + (size_t)(i * 2 + 1) * C_ * C_, bres + (size_t)(i * 2 + 1) * C_,
            bn_res + (size_t)(i * 2 + 1) * 4 * C_, bufH, bufH, MROWS, C_, C_);
    }

    k_pool<<<NSAMP, 256, 0, stream>>>(bufH, bufC, bufF);

    // pred: relu(bn(feats @ Wp1^T + bp1))   (Wp1 is [C, 3C] row-major -> BT mode)
    k_gemm<true, false><<<gp, 256, 0, stream>>>(bufF, Wp1, bp1, bn_pred, nullptr, bufP,
                                                NSAMP, C_, 3 * C_);

    k_final<<<(NSAMP * 2 * J_ + 255) / 256, 256, 0, stream>>>(bufP, Wp2, bp2, out);
}

// Round 3
// 1368.368 us; speedup vs baseline: 2.1807x; 2.1807x over previous
//
#include <hip/hip_runtime.h>
#include <math.h>

#define B_    16
#define NP_   64
#define J_    17
#define C_    480
#define H_    128
#define W_    128
#define L_    4
#define HW_   (H_ * W_)
#define NSAMP (B_ * NP_)      // 1024
#define MROWS (NSAMP * J_)    // 17408
#define EPS_  1e-5f
#define NMAT  (1 + 2 * L_)    // 9 graph-conv weight matrices

typedef __attribute__((ext_vector_type(8))) short bf16x8;
typedef __attribute__((ext_vector_type(4))) float f32x4;

__device__ __forceinline__ unsigned short f2bf(float f) {
    unsigned int u = __float_as_uint(f);
    unsigned int r = (u + 0x7fffu + ((u >> 16) & 1u)) >> 16;
    return (unsigned short)r;
}
__device__ __forceinline__ float bf2f(unsigned short h) {
    return __uint_as_float(((unsigned int)h) << 16);
}

// ---------------- bilinear joint sampling ----------------
__global__ __launch_bounds__(256) void k_sample(const float* __restrict__ feat,
                                                const float* __restrict__ coords,
                                                float* __restrict__ X) {
    int p  = blockIdx.x;          // 0..MROWS-1
    int bn = p / J_;
    int b  = bn / NP_;
    float x = coords[p * 2 + 0];
    float y = coords[p * 2 + 1];
    float x0f = fminf(fmaxf(floorf(x), 0.f), (float)(W_ - 2));
    float y0f = fminf(fmaxf(floorf(y), 0.f), (float)(H_ - 2));
    int x0 = (int)x0f, y0 = (int)y0f;
    float wx = x - x0f, wy = y - y0f;
    float w00 = (1.f - wx) * (1.f - wy);
    float w01 = wx * (1.f - wy);
    float w10 = (1.f - wx) * wy;
    float w11 = wx * wy;
    int i00 = y0 * W_ + x0;
    const float* base = feat + (size_t)b * C_ * HW_;
    for (int c = threadIdx.x; c < C_; c += 256) {
        const float* pc = base + (size_t)c * HW_ + i00;
        float v = pc[0] * w00 + pc[1] * w01 + pc[W_] * w10 + pc[W_ + 1] * w11;
        X[(size_t)p * C_ + c] = v;
    }
}

// ---------------- center gather ----------------
__global__ __launch_bounds__(256) void k_center(const float* __restrict__ feat,
                                                const int* __restrict__ cidx,
                                                float* __restrict__ Cf) {
    int bn = blockIdx.x;
    int b  = bn / NP_;
    int idx = cidx[bn];
    const float* base = feat + (size_t)b * C_ * HW_ + idx;
    for (int c = threadIdx.x; c < C_; c += 256)
        Cf[(size_t)bn * C_ + c] = base[(size_t)c * HW_];
}

// ---------------- weight split+transpose: W[k][n] f32 -> Wt_hi/lo[n][k] bf16 ----------------
__global__ __launch_bounds__(256) void k_wsplit(const float* __restrict__ Wh,
                                                const float* __restrict__ Wres,
                                                short* __restrict__ WtH,
                                                short* __restrict__ WtL) {
    int gid = blockIdx.x * 256 + threadIdx.x;
    if (gid >= NMAT * C_ * C_) return;
    int m   = gid / (C_ * C_);
    int rem = gid % (C_ * C_);
    int n = rem / C_;
    int k = rem % C_;
    const float* src = (m == 0) ? Wh : (Wres + (size_t)(m - 1) * C_ * C_);
    float v = src[(size_t)k * C_ + n];
    unsigned short h = f2bf(v);
    WtH[gid] = (short)h;
    WtL[gid] = (short)f2bf(v - bf2f(h));
}

// ---------------- adjacency mix + bf16 split: A = adj @ X  ->  Ah,Al [MROWS][C] ----------------
__global__ __launch_bounds__(256) void k_mix_split(const float* __restrict__ Xin,
                                                   const float* __restrict__ adj,
                                                   short* __restrict__ Ah,
                                                   short* __restrict__ Al) {
    __shared__ float sadj[J_ * J_];
    for (int t = threadIdx.x; t < J_ * J_; t += 256) sadj[t] = adj[t];
    __syncthreads();
    int n = blockIdx.x;
    const float* xb = Xin + (size_t)n * J_ * C_;
    size_t obase = (size_t)n * J_ * C_;
    for (int c = threadIdx.x; c < C_; c += 256) {
        float xv[J_];
        #pragma unroll
        for (int k = 0; k < J_; k++) xv[k] = xb[(size_t)k * C_ + c];
        #pragma unroll
        for (int j = 0; j < J_; j++) {
            float s = 0.f;
            #pragma unroll
            for (int k = 0; k < J_; k++) s += sadj[j * J_ + k] * xv[k];
            unsigned short h = f2bf(s);
            Ah[obase + (size_t)j * C_ + c] = (short)h;
            Al[obase + (size_t)j * C_ + c] = (short)f2bf(s - bf2f(h));
        }
    }
}

// ---------------- split-bf16 MFMA GEMM, fused bias+BN+ReLU (+residual) ----------------
// out[m,n] = relu(bn(sum_k A[m,k]B[k,n] + bias[n])) (+ res)
// A given as Ah/Al [M][K] bf16 (hi/lo split); B as Bh/Bl [N][K] bf16 (transposed).
// acc = Ah*Bh + Ah*Bl + Al*Bh  (al*bl term ~2^-18, dropped)
// BM=BN=128, BK=32, 256 threads = 4 waves (2x2 of 64x64), mfma_f32_16x16x32_bf16.
template <bool ADD>
__global__ __launch_bounds__(256) void k_gemm_mfma(const short* __restrict__ Ah,
                                                   const short* __restrict__ Al,
                                                   const short* __restrict__ Bh,
                                                   const short* __restrict__ Bl,
                                                   const float* __restrict__ bias,
                                                   const float* __restrict__ bn4,
                                                   const float* res,   // may alias out
                                                   float* out,
                                                   int M, int N, int K) {
    __shared__ short lds[4 * 128 * 32];   // sAh | sAl | sBh | sBl, each [128 rows][32 k] swizzled
    short* sAh = lds;
    short* sAl = lds + 4096;
    short* sBh = lds + 8192;
    short* sBl = lds + 12288;

    const int tid  = threadIdx.x;
    const int lane = tid & 63;
    const int wid  = tid >> 6;
    const int wm0  = (wid >> 1) * 64;
    const int wn0  = (wid & 1) * 64;
    const int row0 = blockIdx.y * 128;
    const int col0 = blockIdx.x * 128;

    f32x4 acc[4][4];
    #pragma unroll
    for (int i = 0; i < 4; i++)
        #pragma unroll
        for (int j = 0; j < 4; j++) acc[i][j] = (f32x4){0.f, 0.f, 0.f, 0.f};

    const int kq = lane >> 4;     // 0..3 : which 8-wide k group
    const int fr = lane & 15;     // fragment row/col

    for (int ks = 0; ks < K / 32; ++ks) {
        const int kk = ks * 32;
        // ---- stage: 512 16B-chunks per tensor; thread t does chunks t and t+256 ----
        #pragma unroll
        for (int h = 0; h < 2; ++h) {
            int c  = tid + h * 256;
            int r  = c >> 2;
            int cq = c & 3;
            int so = ((r * 64 + cq * 16) ^ ((r & 7) << 4)) >> 1;  // short index, swizzled
            size_t ga = (size_t)(row0 + r) * K + kk + cq * 8;
            *reinterpret_cast<int4*>(sAh + so) = *reinterpret_cast<const int4*>(Ah + ga);
            *reinterpret_cast<int4*>(sAl + so) = *reinterpret_cast<const int4*>(Al + ga);
            int4 vh = {0, 0, 0, 0}, vl = {0, 0, 0, 0};
            if (col0 + r < N) {
                size_t gb = (size_t)(col0 + r) * K + kk + cq * 8;
                vh = *reinterpret_cast<const int4*>(Bh + gb);
                vl = *reinterpret_cast<const int4*>(Bl + gb);
            }
            *reinterpret_cast<int4*>(sBh + so) = vh;
            *reinterpret_cast<int4*>(sBl + so) = vl;
        }
        __syncthreads();
        // ---- fragments ----
        bf16x8 fah[4], fal[4], fbh[4], fbl[4];
        #pragma unroll
        for (int mf = 0; mf < 4; ++mf) {
            int r  = wm0 + mf * 16 + fr;
            int so = ((r * 64 + kq * 16) ^ ((r & 7) << 4)) >> 1;
            fah[mf] = *reinterpret_cast<const bf16x8*>(sAh + so);
            fal[mf] = *reinterpret_cast<const bf16x8*>(sAl + so);
        }
        #pragma unroll
        for (int nf = 0; nf < 4; ++nf) {
            int r  = wn0 + nf * 16 + fr;
            int so = ((r * 64 + kq * 16) ^ ((r & 7) << 4)) >> 1;
            fbh[nf] = *reinterpret_cast<const bf16x8*>(sBh + so);
            fbl[nf] = *reinterpret_cast<const bf16x8*>(sBl + so);
        }
        // ---- MFMA: 3-term split product ----
        #pragma unroll
        for (int mf = 0; mf < 4; ++mf)
            #pragma unroll
            for (int nf = 0; nf < 4; ++nf) {
                acc[mf][nf] = __builtin_amdgcn_mfma_f32_16x16x32_bf16(fah[mf], fbh[nf], acc[mf][nf], 0, 0, 0);
                acc[mf][nf] = __builtin_amdgcn_mfma_f32_16x16x32_bf16(fah[mf], fbl[nf], acc[mf][nf], 0, 0, 0);
                acc[mf][nf] = __builtin_amdgcn_mfma_f32_16x16x32_bf16(fal[mf], fbh[nf], acc[mf][nf], 0, 0, 0);
            }
        __syncthreads();
    }

    // ---- epilogue: C/D layout col=lane&15, row=(lane>>4)*4+reg ----
    const int rq = lane >> 4;
    #pragma unroll
    for (int nf = 0; nf < 4; ++nf) {
        int col = col0 + wn0 + nf * 16 + fr;
        if (col >= N) continue;
        float bia = bias[col];
        float g   = bn4[col];
        float be  = bn4[N + col];
        float mu  = bn4[2 * N + col];
        float va  = bn4[3 * N + col];
        float sc  = rsqrtf(va + EPS_) * g;
        #pragma unroll
        for (int mf = 0; mf < 4; ++mf) {
            #pragma unroll
            for (int r = 0; r < 4; ++r) {
                int row = row0 + wm0 + mf * 16 + rq * 4 + r;
                float v = acc[mf][nf][r] + bia;
                v = (v - mu) * sc + be;
                v = fmaxf(v, 0.f);
                if (ADD) v += res[(size_t)row * N + col];
                out[(size_t)row * N + col] = v;
            }
        }
    }
}

// ---------------- f32 tiled GEMM (kept for the pred layer), BT: B is [N,K] ----------------
template <bool BT, bool ADD>
__global__ __launch_bounds__(256) void k_gemm(const float* __restrict__ A,
                                              const float* __restrict__ Bm,
                                              const float* __restrict__ bias,
                                              const float* __restrict__ bn,
                                              const float* res,
                                              float* out,
                                              int M, int N, int K) {
    __shared__ float As[16][132];
    __shared__ float Bs[16][132];
    const int tid = threadIdx.x;
    const int tx = tid & 15, ty = tid >> 4;
    const int row0 = blockIdx.y * 128;
    const int col0 = blockIdx.x * 128;

    float acc[8][8];
    #pragma unroll
    for (int i = 0; i < 8; i++)
        #pragma unroll
        for (int j = 0; j < 8; j++) acc[i][j] = 0.f;

    for (int kk = 0; kk < K; kk += 16) {
        {
            int r  = tid >> 2;
            int v4 = (tid & 3) * 4;
            #pragma unroll
            for (int h = 0; h < 2; h++) {
                int rr = r + h * 64;
                float4 a = *reinterpret_cast<const float4*>(
                    &A[(size_t)(row0 + rr) * K + kk + v4]);
                As[v4 + 0][rr] = a.x;
                As[v4 + 1][rr] = a.y;
                As[v4 + 2][rr] = a.z;
                As[v4 + 3][rr] = a.w;
            }
        }
        if (!BT) {
            int k0 = tid >> 5;
            int c4 = (tid & 31) * 4;
            #pragma unroll
            for (int h = 0; h < 2; h++) {
                int k = k0 + h * 8;
                float4 v = make_float4(0.f, 0.f, 0.f, 0.f);
                int col = col0 + c4;
                if (col < N)
                    v = *reinterpret_cast<const float4*>(&Bm[(size_t)(kk + k) * N + col]);
                *reinterpret_cast<float4*>(&Bs[k][c4]) = v;
            }
        } else {
            int cr = tid >> 2;
            int k4 = (tid & 3) * 4;
            #pragma unroll
            for (int h = 0; h < 2; h++) {
                int cc = cr + h * 64;
                int col = col0 + cc;
                float4 v = make_float4(0.f, 0.f, 0.f, 0.f);
                if (col < N)
                    v = *reinterpret_cast<const float4*>(&Bm[(size_t)col * K + kk + k4]);
                Bs[k4 + 0][cc] = v.x;
                Bs[k4 + 1][cc] = v.y;
                Bs[k4 + 2][cc] = v.z;
                Bs[k4 + 3][cc] = v.w;
            }
        }
        __syncthreads();
        #pragma unroll
        for (int k = 0; k < 16; k++) {
            float4 a0 = *reinterpret_cast<const float4*>(&As[k][ty * 8]);
            float4 a1 = *reinterpret_cast<const float4*>(&As[k][ty * 8 + 4]);
            float4 b0 = *reinterpret_cast<const float4*>(&Bs[k][tx * 8]);
            float4 b1 = *reinterpret_cast<const float4*>(&Bs[k][tx * 8 + 4]);
            float av[8] = {a0.x, a0.y, a0.z, a0.w, a1.x, a1.y, a1.z, a1.w};
            float bv[8] = {b0.x, b0.y, b0.z, b0.w, b1.x, b1.y, b1.z, b1.w};
            #pragma unroll
            for (int i = 0; i < 8; i++)
                #pragma unroll
                for (int j = 0; j < 8; j++)
                    acc[i][j] = fmaf(av[i], bv[j], acc[i][j]);
        }
        __syncthreads();
    }

    #pragma unroll
    for (int i = 0; i < 8; i++) {
        int row = row0 + ty * 8 + i;
        #pragma unroll
        for (int j = 0; j < 8; j++) {
            int col = col0 + tx * 8 + j;
            if (col < N) {
                float v  = acc[i][j] + bias[col];
                float g  = bn[col];
                float be = bn[N + col];
                float mu = bn[2 * N + col];
                float va = bn[3 * N + col];
                v = (v - mu) * rsqrtf(va + EPS_) * g + be;
                v = fmaxf(v, 0.f);
                if (ADD) v += res[(size_t)row * N + col];
                out[(size_t)row * N + col] = v;
            }
        }
    }
}

// ---------------- pooling + concat ----------------
__global__ __launch_bounds__(256) void k_pool(const float* __restrict__ Hb,
                                              const float* __restrict__ Cen,
                                              float* __restrict__ feats) {
    int n = blockIdx.x;
    for (int c = threadIdx.x; c < C_; c += 256) {
        float s = 0.f, m = -INFINITY;
        #pragma unroll
        for (int j = 0; j < J_; j++) {
            float v = Hb[((size_t)n * J_ + j) * C_ + c];
            s += v;
            m = fmaxf(m, v);
        }
        feats[(size_t)n * 3 * C_ + c]          = s * (1.f / (float)J_);
        feats[(size_t)n * 3 * C_ + C_ + c]     = m;
        feats[(size_t)n * 3 * C_ + 2 * C_ + c] = Cen[(size_t)n * C_ + c];
    }
}

// ---------------- final projection ----------------
__global__ __launch_bounds__(256) void k_final(const float* __restrict__ P,
                                               const float* __restrict__ W2,
                                               const float* __restrict__ b2,
                                               float* __restrict__ out) {
    int g = blockIdx.x * 256 + threadIdx.x;
    if (g >= NSAMP * 2 * J_) return;
    int m = g / (2 * J_);
    int o = g % (2 * J_);
    const float* pr = P + (size_t)m * C_;
    const float* wr = W2 + (size_t)o * C_;
    float s = 0.f;
    for (int k = 0; k < C_; k += 4) {
        s = fmaf(pr[k + 0], wr[k + 0], s);
        s = fmaf(pr[k + 1], wr[k + 1], s);
        s = fmaf(pr[k + 2], wr[k + 2], s);
        s = fmaf(pr[k + 3], wr[k + 3], s);
    }
    out[g] = s + b2[o];
}

extern "C" void kernel_launch(void* const* d_in, const int* in_sizes, int n_in,
                              void* d_out, int out_size, void* d_ws, size_t ws_size,
                              hipStream_t stream) {
    const float* features = (const float*)d_in[0];
    const float* coords   = (const float*)d_in[1];
    const int*   center   = (const int*)d_in[2];
    const float* adj      = (const float*)d_in[3];
    const float* Wh       = (const float*)d_in[4];
    const float* bh       = (const float*)d_in[5];
    const float* bn_head  = (const float*)d_in[6];
    const float* Wres     = (const float*)d_in[7];
    const float* bres     = (const float*)d_in[8];
    const float* bn_res   = (const float*)d_in[9];
    const float* Wp1      = (const float*)d_in[10];
    const float* bp1      = (const float*)d_in[11];
    const float* bn_pred  = (const float*)d_in[12];
    const float* Wp2      = (const float*)d_in[13];
    const float* bp2      = (const float*)d_in[14];
    float* out = (float*)d_out;

    // ---- workspace layout (all offsets 256B-aligned) ----
    char* ws = (char*)d_ws;
    float* bufX = (float*)ws;                          ws += (size_t)MROWS * C_ * 4;   // f32 [MROWS,C]
    float* bufH = (float*)ws;                          ws += (size_t)MROWS * C_ * 4;
    short* AhB  = (short*)ws;                          ws += (size_t)MROWS * C_ * 2;   // bf16 hi
    short* AlB  = (short*)ws;                          ws += (size_t)MROWS * C_ * 2;   // bf16 lo
    float* bufC = (float*)ws;                          ws += (size_t)NSAMP * C_ * 4;
    float* bufF = (float*)ws;                          ws += (size_t)NSAMP * 3 * C_ * 4;
    float* bufP = (float*)ws;                          ws += (size_t)NSAMP * C_ * 4;
    short* WtH  = (short*)ws;                          ws += (size_t)NMAT * C_ * C_ * 2;
    short* WtL  = (short*)ws;                          ws += (size_t)NMAT * C_ * C_ * 2;

    dim3 gg(4, MROWS / 128);   // MFMA gemm grid: N=480 -> 4 col tiles (last masked)
    dim3 gp(4, NSAMP / 128);

    k_wsplit<<<(NMAT * C_ * C_ + 255) / 256, 256, 0, stream>>>(Wh, Wres, WtH, WtL);
    k_sample<<<MROWS, 256, 0, stream>>>(features, coords, bufX);
    k_center<<<NSAMP, 256, 0, stream>>>(features, center, bufC);

    // head block
    k_mix_split<<<NSAMP, 256, 0, stream>>>(bufX, adj, AhB, AlB);
    k_gemm_mfma<false><<<gg, 256, 0, stream>>>(AhB, AlB, WtH, WtL, bh, bn_head,
                                               nullptr, bufH, MROWS, C_, C_);

    for (int i = 0; i < L_; i++) {
        int m1 = 1 + 2 * i, m2 = 2 + 2 * i;
        k_mix_split<<<NSAMP, 256, 0, stream>>>(bufH, adj, AhB, AlB);
        k_gemm_mfma<false><<<gg, 256, 0, stream>>>(
            AhB, AlB, WtH + (size_t)m1 * C_ * C_, WtL + (size_t)m1 * C_ * C_,
            bres + (size_t)(2 * i) * C_, bn_res + (size_t)(2 * i) * 4 * C_,
            nullptr, bufX, MROWS, C_, C_);
        k_mix_split<<<NSAMP, 256, 0, stream>>>(bufX, adj, AhB, AlB);
        k_gemm_mfma<true><<<gg, 256, 0, stream>>>(
            AhB, AlB, WtH + (size_t)m2 * C_ * C_, WtL + (size_t)m2 * C_ * C_,
            bres + (size_t)(2 * i + 1) * C_, bn_res + (size_t)(2 * i + 1) * 4 * C_,
            bufH, bufH, MROWS, C_, C_);
    }

    k_pool<<<NSAMP, 256, 0, stream>>>(bufH, bufC, bufF);

    k_gemm<true, false><<<gp, 256, 0, stream>>>(bufF, Wp1, bp1, bn_pred, nullptr, bufP,
                                                NSAMP, C_, 3 * C_);

    k_final<<<(NSAMP * 2 * J_ + 255) / 256, 256, 0, stream>>>(bufP, Wp2, bp2, out);
}

// Round 4
// 1082.863 us; speedup vs baseline: 2.7556x; 1.2637x over previous
//
#include <hip/hip_runtime.h>
#include <math.h>

#define B_    16
#define NP_   64
#define J_    17
#define C_    480
#define H_    128
#define W_    128
#define L_    4
#define HW_   (H_ * W_)
#define NSAMP (B_ * NP_)      // 1024
#define MROWS (NSAMP * J_)    // 17408
#define EPS_  1e-5f
#define NMAT  (1 + 2 * L_)    // 9 graph-conv weight matrices

typedef __attribute__((ext_vector_type(8))) short bf16x8;
typedef __attribute__((ext_vector_type(4))) float f32x4;

__device__ __forceinline__ unsigned short f2bf(float f) {
    unsigned int u = __float_as_uint(f);
    unsigned int r = (u + 0x7fffu + ((u >> 16) & 1u)) >> 16;
    return (unsigned short)r;
}
__device__ __forceinline__ float bf2f(unsigned short h) {
    return __uint_as_float(((unsigned int)h) << 16);
}

// ---------------- bilinear joint sampling ----------------
__global__ __launch_bounds__(256) void k_sample(const float* __restrict__ feat,
                                                const float* __restrict__ coords,
                                                float* __restrict__ X) {
    int p  = blockIdx.x;          // 0..MROWS-1
    int bn = p / J_;
    int b  = bn / NP_;
    float x = coords[p * 2 + 0];
    float y = coords[p * 2 + 1];
    float x0f = fminf(fmaxf(floorf(x), 0.f), (float)(W_ - 2));
    float y0f = fminf(fmaxf(floorf(y), 0.f), (float)(H_ - 2));
    int x0 = (int)x0f, y0 = (int)y0f;
    float wx = x - x0f, wy = y - y0f;
    float w00 = (1.f - wx) * (1.f - wy);
    float w01 = wx * (1.f - wy);
    float w10 = (1.f - wx) * wy;
    float w11 = wx * wy;
    int i00 = y0 * W_ + x0;
    const float* base = feat + (size_t)b * C_ * HW_;
    for (int c = threadIdx.x; c < C_; c += 256) {
        const float* pc = base + (size_t)c * HW_ + i00;
        float v = pc[0] * w00 + pc[1] * w01 + pc[W_] * w10 + pc[W_ + 1] * w11;
        X[(size_t)p * C_ + c] = v;
    }
}

// ---------------- center gather ----------------
__global__ __launch_bounds__(256) void k_center(const float* __restrict__ feat,
                                                const int* __restrict__ cidx,
                                                float* __restrict__ Cf) {
    int bn = blockIdx.x;
    int b  = bn / NP_;
    int idx = cidx[bn];
    const float* base = feat + (size_t)b * C_ * HW_ + idx;
    for (int c = threadIdx.x; c < C_; c += 256)
        Cf[(size_t)bn * C_ + c] = base[(size_t)c * HW_];
}

// ---------------- weight split: conv W[k][n] -> Wt hi/lo [n][k]; Wp1 [n][k] -> hi/lo ----------------
__global__ __launch_bounds__(256) void k_wsplit(const float* __restrict__ Wh,
                                                const float* __restrict__ Wres,
                                                const float* __restrict__ Wp1,
                                                short* __restrict__ WtH,
                                                short* __restrict__ WtL,
                                                short* __restrict__ WpH,
                                                short* __restrict__ WpL) {
    int gid = blockIdx.x * 256 + threadIdx.x;
    const int t1 = NMAT * C_ * C_;
    const int t2 = C_ * 3 * C_;
    if (gid < t1) {
        int m   = gid / (C_ * C_);
        int rem = gid % (C_ * C_);
        int n = rem / C_;
        int k = rem % C_;
        const float* src = (m == 0) ? Wh : (Wres + (size_t)(m - 1) * C_ * C_);
        float v = src[(size_t)k * C_ + n];
        unsigned short h = f2bf(v);
        WtH[gid] = (short)h;
        WtL[gid] = (short)f2bf(v - bf2f(h));
    } else if (gid < t1 + t2) {
        int g2 = gid - t1;
        float v = Wp1[g2];          // already [N=480][K=1440]
        unsigned short h = f2bf(v);
        WpH[g2] = (short)h;
        WpL[g2] = (short)f2bf(v - bf2f(h));
    }
}

// ---------------- adjacency mix -> bf16 A [MROWS][C] ----------------
__global__ __launch_bounds__(256) void k_mix_bf16(const float* __restrict__ Xin,
                                                  const float* __restrict__ adj,
                                                  short* __restrict__ Ah) {
    __shared__ float sadj[J_ * J_];
    for (int t = threadIdx.x; t < J_ * J_; t += 256) sadj[t] = adj[t];
    __syncthreads();
    int n = blockIdx.x;
    const float* xb = Xin + (size_t)n * J_ * C_;
    size_t obase = (size_t)n * J_ * C_;
    for (int c = threadIdx.x; c < C_; c += 256) {
        float xv[J_];
        #pragma unroll
        for (int k = 0; k < J_; k++) xv[k] = xb[(size_t)k * C_ + c];
        #pragma unroll
        for (int j = 0; j < J_; j++) {
            float s = 0.f;
            #pragma unroll
            for (int k = 0; k < J_; k++) s += sadj[j * J_ + k] * xv[k];
            Ah[obase + (size_t)j * C_ + c] = (short)f2bf(s);
        }
    }
}

// ---------------- 2-term split MFMA GEMM, fused bias+BN+ReLU (+residual) ----------------
// out[m,n] = relu(bn(sum_k A[m,k]B[k,n] + bias[n])) (+ res)
// A bf16 [M][K]; B split Bh/Bl bf16 [N][K] (transposed). acc = A*Bh + A*Bl.
// BM=BN=128, BK=32, 256 threads = 4 waves (2x2 of 64x64), mfma_f32_16x16x32_bf16.
template <bool ADD>
__global__ __launch_bounds__(256) void k_gemm_mfma(const short* __restrict__ A,
                                                   const short* __restrict__ Bh,
                                                   const short* __restrict__ Bl,
                                                   const float* __restrict__ bias,
                                                   const float* __restrict__ bn4,
                                                   const float* res,   // may alias out
                                                   float* out,
                                                   int M, int N, int K) {
    __shared__ short lds[3 * 4096];   // sA | sBh | sBl, each [128 rows][32 k] swizzled (8 KB)
    short* sA  = lds;
    short* sBh = lds + 4096;
    short* sBl = lds + 8192;

    const int tid  = threadIdx.x;
    const int lane = tid & 63;
    const int wid  = tid >> 6;
    const int wm0  = (wid >> 1) * 64;
    const int wn0  = (wid & 1) * 64;
    const int row0 = blockIdx.y * 128;
    const int col0 = blockIdx.x * 128;

    f32x4 acc[4][4];
    #pragma unroll
    for (int i = 0; i < 4; i++)
        #pragma unroll
        for (int j = 0; j < 4; j++) acc[i][j] = (f32x4){0.f, 0.f, 0.f, 0.f};

    const int kq = lane >> 4;     // 0..3 : which 8-wide k group
    const int fr = lane & 15;

    for (int ks = 0; ks < K / 32; ++ks) {
        const int kk = ks * 32;
        // ---- stage: per tensor 512 16B-chunks; thread t does chunks t and t+256 ----
        #pragma unroll
        for (int h = 0; h < 2; ++h) {
            int c  = tid + h * 256;
            int r  = c >> 2;
            int cq = c & 3;
            int so = ((r * 64 + cq * 16) ^ ((r & 7) << 4)) >> 1;  // short idx, swizzled
            size_t ga = (size_t)(row0 + r) * K + kk + cq * 8;
            *reinterpret_cast<int4*>(sA + so) = *reinterpret_cast<const int4*>(A + ga);
            int4 vh = {0, 0, 0, 0}, vl = {0, 0, 0, 0};
            if (col0 + r < N) {
                size_t gb = (size_t)(col0 + r) * K + kk + cq * 8;
                vh = *reinterpret_cast<const int4*>(Bh + gb);
                vl = *reinterpret_cast<const int4*>(Bl + gb);
            }
            *reinterpret_cast<int4*>(sBh + so) = vh;
            *reinterpret_cast<int4*>(sBl + so) = vl;
        }
        __syncthreads();
        // ---- fragments ----
        bf16x8 fa[4], fbh[4], fbl[4];
        #pragma unroll
        for (int mf = 0; mf < 4; ++mf) {
            int r  = wm0 + mf * 16 + fr;
            int so = ((r * 64 + kq * 16) ^ ((r & 7) << 4)) >> 1;
            fa[mf] = *reinterpret_cast<const bf16x8*>(sA + so);
        }
        #pragma unroll
        for (int nf = 0; nf < 4; ++nf) {
            int r  = wn0 + nf * 16 + fr;
            int so = ((r * 64 + kq * 16) ^ ((r & 7) << 4)) >> 1;
            fbh[nf] = *reinterpret_cast<const bf16x8*>(sBh + so);
            fbl[nf] = *reinterpret_cast<const bf16x8*>(sBl + so);
        }
        // ---- MFMA: 2-term split product ----
        #pragma unroll
        for (int mf = 0; mf < 4; ++mf)
            #pragma unroll
            for (int nf = 0; nf < 4; ++nf) {
                acc[mf][nf] = __builtin_amdgcn_mfma_f32_16x16x32_bf16(fa[mf], fbh[nf], acc[mf][nf], 0, 0, 0);
                acc[mf][nf] = __builtin_amdgcn_mfma_f32_16x16x32_bf16(fa[mf], fbl[nf], acc[mf][nf], 0, 0, 0);
            }
        __syncthreads();
    }

    // ---- epilogue: C/D layout col=lane&15, row=(lane>>4)*4+reg ----
    const int rq = lane >> 4;
    #pragma unroll
    for (int nf = 0; nf < 4; ++nf) {
        int col = col0 + wn0 + nf * 16 + fr;
        if (col >= N) continue;
        float bia = bias[col];
        float g   = bn4[col];
        float be  = bn4[N + col];
        float mu  = bn4[2 * N + col];
        float va  = bn4[3 * N + col];
        float sc  = rsqrtf(va + EPS_) * g;
        #pragma unroll
        for (int mf = 0; mf < 4; ++mf) {
            #pragma unroll
            for (int r = 0; r < 4; ++r) {
                int row = row0 + wm0 + mf * 16 + rq * 4 + r;
                float v = acc[mf][nf][r] + bia;
                v = (v - mu) * sc + be;
                v = fmaxf(v, 0.f);
                if (ADD) v += res[(size_t)row * N + col];
                out[(size_t)row * N + col] = v;
            }
        }
    }
}

// ---------------- pooling + concat -> bf16 feats [NSAMP][3C] ----------------
__global__ __launch_bounds__(256) void k_pool(const float* __restrict__ Hb,
                                              const float* __restrict__ Cen,
                                              short* __restrict__ feats) {
    int n = blockIdx.x;
    for (int c = threadIdx.x; c < C_; c += 256) {
        float s = 0.f, m = -INFINITY;
        #pragma unroll
        for (int j = 0; j < J_; j++) {
            float v = Hb[((size_t)n * J_ + j) * C_ + c];
            s += v;
            m = fmaxf(m, v);
        }
        feats[(size_t)n * 3 * C_ + c]          = (short)f2bf(s * (1.f / (float)J_));
        feats[(size_t)n * 3 * C_ + C_ + c]     = (short)f2bf(m);
        feats[(size_t)n * 3 * C_ + 2 * C_ + c] = (short)f2bf(Cen[(size_t)n * C_ + c]);
    }
}

// ---------------- final projection ----------------
__global__ __launch_bounds__(256) void k_final(const float* __restrict__ P,
                                               const float* __restrict__ W2,
                                               const float* __restrict__ b2,
                                               float* __restrict__ out) {
    int g = blockIdx.x * 256 + threadIdx.x;
    if (g >= NSAMP * 2 * J_) return;
    int m = g / (2 * J_);
    int o = g % (2 * J_);
    const float* pr = P + (size_t)m * C_;
    const float* wr = W2 + (size_t)o * C_;
    float s = 0.f;
    for (int k = 0; k < C_; k += 4) {
        s = fmaf(pr[k + 0], wr[k + 0], s);
        s = fmaf(pr[k + 1], wr[k + 1], s);
        s = fmaf(pr[k + 2], wr[k + 2], s);
        s = fmaf(pr[k + 3], wr[k + 3], s);
    }
    out[g] = s + b2[o];
}

extern "C" void kernel_launch(void* const* d_in, const int* in_sizes, int n_in,
                              void* d_out, int out_size, void* d_ws, size_t ws_size,
                              hipStream_t stream) {
    const float* features = (const float*)d_in[0];
    const float* coords   = (const float*)d_in[1];
    const int*   center   = (const int*)d_in[2];
    const float* adj      = (const float*)d_in[3];
    const float* Wh       = (const float*)d_in[4];
    const float* bh       = (const float*)d_in[5];
    const float* bn_head  = (const float*)d_in[6];
    const float* Wres     = (const float*)d_in[7];
    const float* bres     = (const float*)d_in[8];
    const float* bn_res   = (const float*)d_in[9];
    const float* Wp1      = (const float*)d_in[10];
    const float* bp1      = (const float*)d_in[11];
    const float* bn_pred  = (const float*)d_in[12];
    const float* Wp2      = (const float*)d_in[13];
    const float* bp2      = (const float*)d_in[14];
    float* out = (float*)d_out;

    // ---- workspace layout ----
    char* ws = (char*)d_ws;
    float* bufX  = (float*)ws;   ws += (size_t)MROWS * C_ * 4;       // f32 [MROWS,C]
    float* bufH  = (float*)ws;   ws += (size_t)MROWS * C_ * 4;
    short* AhB   = (short*)ws;   ws += (size_t)MROWS * C_ * 2;       // bf16 A
    float* bufC  = (float*)ws;   ws += (size_t)NSAMP * C_ * 4;
    short* featsB= (short*)ws;   ws += (size_t)NSAMP * 3 * C_ * 2;   // bf16 feats
    float* bufP  = (float*)ws;   ws += (size_t)NSAMP * C_ * 4;
    short* WtH   = (short*)ws;   ws += (size_t)NMAT * C_ * C_ * 2;
    short* WtL   = (short*)ws;   ws += (size_t)NMAT * C_ * C_ * 2;
    short* WpH   = (short*)ws;   ws += (size_t)C_ * 3 * C_ * 2;
    short* WpL   = (short*)ws;   ws += (size_t)C_ * 3 * C_ * 2;

    dim3 gg(4, MROWS / 128);   // conv GEMMs: N=480 -> 4 col tiles (last masked)
    dim3 gp(4, NSAMP / 128);   // pred GEMM

    int wtot = NMAT * C_ * C_ + C_ * 3 * C_;
    k_wsplit<<<(wtot + 255) / 256, 256, 0, stream>>>(Wh, Wres, Wp1, WtH, WtL, WpH, WpL);
    k_sample<<<MROWS, 256, 0, stream>>>(features, coords, bufX);
    k_center<<<NSAMP, 256, 0, stream>>>(features, center, bufC);

    // head block
    k_mix_bf16<<<NSAMP, 256, 0, stream>>>(bufX, adj, AhB);
    k_gemm_mfma<false><<<gg, 256, 0, stream>>>(AhB, WtH, WtL, bh, bn_head,
                                               nullptr, bufH, MROWS, C_, C_);

    for (int i = 0; i < L_; i++) {
        int m1 = 1 + 2 * i, m2 = 2 + 2 * i;
        k_mix_bf16<<<NSAMP, 256, 0, stream>>>(bufH, adj, AhB);
        k_gemm_mfma<false><<<gg, 256, 0, stream>>>(
            AhB, WtH + (size_t)m1 * C_ * C_, WtL + (size_t)m1 * C_ * C_,
            bres + (size_t)(2 * i) * C_, bn_res + (size_t)(2 * i) * 4 * C_,
            nullptr, bufX, MROWS, C_, C_);
        k_mix_bf16<<<NSAMP, 256, 0, stream>>>(bufX, adj, AhB);
        k_gemm_mfma<true><<<gg, 256, 0, stream>>>(
            AhB, WtH + (size_t)m2 * C_ * C_, WtL + (size_t)m2 * C_ * C_,
            bres + (size_t)(2 * i + 1) * C_, bn_res + (size_t)(2 * i + 1) * 4 * C_,
            bufH, bufH, MROWS, C_, C_);
    }

    k_pool<<<NSAMP, 256, 0, stream>>>(bufH, bufC, featsB);

    // pred: relu(bn(feats @ Wp1^T + bp1)) via 2-term MFMA; M=1024, N=480, K=1440
    k_gemm_mfma<false><<<gp, 256, 0, stream>>>(featsB, WpH, WpL, bp1, bn_pred,
                                               nullptr, bufP, NSAMP, C_, 3 * C_);

    k_final<<<(NSAMP * 2 * J_ + 255) / 256, 256, 0, stream>>>(bufP, Wp2, bp2, out);
}